// Round 10
// baseline (495.469 us; speedup 1.0000x reference)
//
#include <hip/hip_runtime.h>
#include <hip/hip_cooperative_groups.h>

namespace cg = cooperative_groups;

#define D 128
#define BKT_SHIFT 9
#define BKT_SIZE 512
#define P1_EPB 4096
#define SW_LDU 68   // uints per W row in LDS (136 ushorts = 128 + 8 pad)

typedef __attribute__((ext_vector_type(8))) short bf16x8;
typedef __attribute__((ext_vector_type(4))) float f32x4;

__device__ inline unsigned int pack2bf(float a, float b) {
    unsigned int ua = __float_as_uint(a);
    unsigned int ub = __float_as_uint(b);
    ua = (ua + 0x7fffu + ((ua >> 16) & 1u)) >> 16;   // RNE
    ub = (ub + 0x7fffu + ((ub >> 16) & 1u)) >> 16;
    return ua | (ub << 16);
}
__device__ inline unsigned short pack1bf(float a) {
    unsigned int ua = __float_as_uint(a);
    return (unsigned short)((ua + 0x7fffu + ((ua >> 16) & 1u)) >> 16);
}

// ===================== single cooperative mega-kernel =====================
// Phase 0: block 0 zeroes bucketCur + work counters.
// Phase 1: p1 partition (grid-stride over edge chunks).
// Phase 2: bucket sort (items [0,nbk)) + GEMM z=bf16(h@W^T) (items [nbk,..))
//          via atomic work-stealing.
// Phase 3: gather+bias+relu via atomic work-stealing (16 nodes per item).
// Bodies identical to the proven round-9 split kernels.

union MegaLDS {
    struct { int hist[256]; int lbase[256]; int gbase[256]; int cur[256];
             unsigned int buf[P1_EPB]; unsigned char bkt8[P1_EPB]; } p1;   // 24.6 KB
    struct { int hist[BKT_SIZE]; int cur[BKT_SIZE]; int sb[256]; } s;      // 4.25 KB
    unsigned int sW[128 * SW_LDU];                                          // 34.8 KB
};

__global__ void mega_kernel(
    const int* __restrict__ esrc, const int* __restrict__ edst,
    const float* __restrict__ h, const float* __restrict__ W,
    const float* __restrict__ b, float* __restrict__ out,
    int* __restrict__ bucketCur, int* __restrict__ gstart,
    int* __restrict__ gend, int* __restrict__ sorted_src,
    unsigned int* __restrict__ pairs, unsigned short* __restrict__ z,
    int* __restrict__ counters,
    int n_nodes, int n_edges, int nbk, int cap, int nchunks,
    int gemmBlocks, int nGather)
{
    cg::grid_group grid = cg::this_grid();
    __shared__ MegaLDS u;
    __shared__ int s_item;
    const int tid = threadIdx.x;

    // ---------- phase 0: init ----------
    if (blockIdx.x == 0) {
        if (tid < nbk) bucketCur[tid] = 0;
        if (tid < 16) counters[tid] = 0;
    }
    grid.sync();

    // ---------- phase 1: partition ----------
    for (int c = blockIdx.x; c < nchunks; c += gridDim.x) {
        const int base = c * P1_EPB;
        u.p1.hist[tid] = 0;
        __syncthreads();
        unsigned int pk[16]; int bk[16];
        #pragma unroll
        for (int k = 0; k < 16; k++) {
            int e = base + k * 256 + tid;
            if (e < n_edges) {
                int sv = esrc[e], dv = edst[e];
                bk[k] = dv >> BKT_SHIFT;
                pk[k] = ((unsigned)sv << BKT_SHIFT) | (unsigned)(dv & (BKT_SIZE - 1));
                atomicAdd(&u.p1.hist[bk[k]], 1);
            } else bk[k] = -1;
        }
        __syncthreads();
        const int v = u.p1.hist[tid];
        if (v > 0) {
            int res = atomicAdd(&bucketCur[tid], v);
            if (res > cap) res = cap;
            u.p1.gbase[tid] = tid * cap + res;
        }
        u.p1.lbase[tid] = v;
        __syncthreads();
        #pragma unroll
        for (int off = 1; off < 256; off <<= 1) {
            int x = (tid >= off) ? u.p1.lbase[tid - off] : 0;
            __syncthreads();
            u.p1.lbase[tid] += x;
            __syncthreads();
        }
        const int excl = u.p1.lbase[tid] - v;
        __syncthreads();
        u.p1.lbase[tid] = excl;
        u.p1.cur[tid] = excl;
        __syncthreads();
        #pragma unroll
        for (int k = 0; k < 16; k++) {
            if (bk[k] >= 0) {
                int loc = atomicAdd(&u.p1.cur[bk[k]], 1);
                u.p1.buf[loc] = pk[k];
                u.p1.bkt8[loc] = (unsigned char)bk[k];
            }
        }
        __syncthreads();
        const int total = min(P1_EPB, n_edges - base);
        for (int i = tid; i < total; i += 256) {
            int bb = u.p1.bkt8[i];
            pairs[(size_t)u.p1.gbase[bb] + (i - u.p1.lbase[bb])] = u.p1.buf[i];
        }
        __syncthreads();
    }
    grid.sync();

    // ---------- phase 2: sort + gemm (work-stealing) ----------
    const int nItems2 = nbk + gemmBlocks;
    while (true) {
        __syncthreads();
        if (tid == 0) s_item = atomicAdd(&counters[0], 1);
        __syncthreads();
        const int it = s_item;
        if (it >= nItems2) break;

        if (it < nbk) {
            // ----- bucket sort -----
            const int bkt = it;
            const int nbase = bkt << BKT_SHIFT;
            const int pstart = bkt * cap;
            int cnt = bucketCur[bkt];
            if (cnt > cap) cnt = cap;
            const int pend = pstart + cnt;
            u.s.hist[tid] = 0; u.s.hist[tid + 256] = 0;
            __syncthreads();
            {
                int j = pstart + tid;
                for (; j + 768 < pend; j += 1024) {
                    unsigned int q0 = pairs[j];
                    unsigned int q1 = pairs[j + 256];
                    unsigned int q2 = pairs[j + 512];
                    unsigned int q3 = pairs[j + 768];
                    atomicAdd(&u.s.hist[q0 & (BKT_SIZE - 1)], 1);
                    atomicAdd(&u.s.hist[q1 & (BKT_SIZE - 1)], 1);
                    atomicAdd(&u.s.hist[q2 & (BKT_SIZE - 1)], 1);
                    atomicAdd(&u.s.hist[q3 & (BKT_SIZE - 1)], 1);
                }
                for (; j < pend; j += 256)
                    atomicAdd(&u.s.hist[pairs[j] & (BKT_SIZE - 1)], 1);
            }
            __syncthreads();
            int a  = u.s.hist[2 * tid];
            int b2 = u.s.hist[2 * tid + 1];
            int psum = a + b2;
            u.s.sb[tid] = psum;
            __syncthreads();
            #pragma unroll
            for (int off = 1; off < 256; off <<= 1) {
                int x = (tid >= off) ? u.s.sb[tid - off] : 0;
                __syncthreads();
                u.s.sb[tid] += x;
                __syncthreads();
            }
            int pexcl = u.s.sb[tid] - psum;
            u.s.cur[2 * tid] = pexcl;
            u.s.cur[2 * tid + 1] = pexcl + a;
            __syncthreads();
            for (int i = tid; i < BKT_SIZE; i += 256) {
                int nd = nbase + i;
                if (nd < n_nodes) {
                    int st = pstart + u.s.cur[i];
                    gstart[nd] = st;
                    gend[nd] = st + u.s.hist[i];
                }
            }
            __syncthreads();
            {
                int j = pstart + tid;
                for (; j + 768 < pend; j += 1024) {
                    unsigned int q0 = pairs[j];
                    unsigned int q1 = pairs[j + 256];
                    unsigned int q2 = pairs[j + 512];
                    unsigned int q3 = pairs[j + 768];
                    int p0 = pstart + atomicAdd(&u.s.cur[q0 & (BKT_SIZE - 1)], 1);
                    int p1 = pstart + atomicAdd(&u.s.cur[q1 & (BKT_SIZE - 1)], 1);
                    int p2 = pstart + atomicAdd(&u.s.cur[q2 & (BKT_SIZE - 1)], 1);
                    int p3 = pstart + atomicAdd(&u.s.cur[q3 & (BKT_SIZE - 1)], 1);
                    sorted_src[p0] = (int)(q0 >> BKT_SHIFT);
                    sorted_src[p1] = (int)(q1 >> BKT_SHIFT);
                    sorted_src[p2] = (int)(q2 >> BKT_SHIFT);
                    sorted_src[p3] = (int)(q3 >> BKT_SHIFT);
                }
                for (; j < pend; j += 256) {
                    unsigned int p = pairs[j];
                    int local = p & (BKT_SIZE - 1);
                    int pos = pstart + atomicAdd(&u.s.cur[local], 1);
                    sorted_src[pos] = (int)(p >> BKT_SHIFT);
                }
            }
        } else {
            // ----- GEMM tile -----
            const int gbid = it - nbk;
            for (int i = tid; i < 4096; i += 256) {
                float4 w = ((const float4*)W)[i];
                int row = i >> 5, c4 = i & 31;
                unsigned int* dst = &u.sW[row * SW_LDU + c4 * 2];
                dst[0] = pack2bf(w.x, w.y);
                dst[1] = pack2bf(w.z, w.w);
            }
            __syncthreads();

            const int wave = tid >> 6;
            const int lane = tid & 63;
            const int m = lane & 15;
            const int q = lane >> 4;
            const int r0 = gbid * 64 + wave * 16;
            const int arow = r0 + m;
            const bool rvalid = arow < n_nodes;

            bf16x8 afrag[4];
            #pragma unroll
            for (int ks = 0; ks < 4; ks++) {
                float4 x = make_float4(0.f, 0.f, 0.f, 0.f), y = x;
                if (rvalid) {
                    const float4* p = (const float4*)(h + (size_t)arow * D + ks * 32 + q * 8);
                    x = p[0]; y = p[1];
                }
                union { unsigned int uu[4]; bf16x8 v; } cvt;
                cvt.uu[0] = pack2bf(x.x, x.y);
                cvt.uu[1] = pack2bf(x.z, x.w);
                cvt.uu[2] = pack2bf(y.x, y.y);
                cvt.uu[3] = pack2bf(y.z, y.w);
                afrag[ks] = cvt.v;
            }

            f32x4 acc[8];
            #pragma unroll
            for (int ct = 0; ct < 8; ct++) acc[ct] = (f32x4){0.f, 0.f, 0.f, 0.f};

            #pragma unroll
            for (int ct = 0; ct < 8; ct++) {
                #pragma unroll
                for (int ks = 0; ks < 4; ks++) {
                    const unsigned int* p = &u.sW[(ct * 16 + m) * SW_LDU + ks * 16 + q * 4];
                    union { uint4 uu; bf16x8 v; } bu;
                    bu.uu = *(const uint4*)p;
                    acc[ct] = __builtin_amdgcn_mfma_f32_16x16x32_bf16(afrag[ks], bu.v, acc[ct], 0, 0, 0);
                }
            }

            __syncthreads();
            unsigned short* lds_us = (unsigned short*)u.sW;
            #pragma unroll
            for (int ct = 0; ct < 8; ct++) {
                #pragma unroll
                for (int i = 0; i < 4; i++) {
                    lds_us[(wave * 16 + q * 4 + i) * 130 + ct * 16 + m] = pack1bf(acc[ct][i]);
                }
            }
            __syncthreads();
            const unsigned int* lds32 = (const unsigned int*)u.sW;
            const int r0blk = gbid * 64;
            #pragma unroll
            for (int pass = 0; pass < 4; pass++) {
                int idx = pass * 256 + tid;
                int row = idx >> 4;
                int c16 = idx & 15;
                int r = r0blk + row;
                if (r < n_nodes) {
                    int bo = row * 65 + c16 * 4;
                    uint4 val;
                    val.x = lds32[bo]; val.y = lds32[bo + 1];
                    val.z = lds32[bo + 2]; val.w = lds32[bo + 3];
                    ((uint4*)z)[(size_t)r * 16 + c16] = val;
                }
            }
        }
    }
    grid.sync();

    // ---------- phase 3: gather + bias + relu (work-stealing) ----------
    const uint4* __restrict__ z4 = (const uint4*)z;
    while (true) {
        __syncthreads();
        if (tid == 0) s_item = atomicAdd(&counters[8], 1);
        __syncthreads();
        const int it = s_item;
        if (it >= nGather) break;
        const int node = it * 16 + (tid >> 4);
        const int lane = tid & 15;
        if (node < n_nodes) {
            int e = gstart[node];
            const int end = gend[node];
            float acc[8];
            #pragma unroll
            for (int i = 0; i < 8; i++) acc[i] = 0.f;
#define ADDV(v) do { \
    acc[0] += __uint_as_float((v).x << 16); acc[1] += __uint_as_float((v).x & 0xffff0000u); \
    acc[2] += __uint_as_float((v).y << 16); acc[3] += __uint_as_float((v).y & 0xffff0000u); \
    acc[4] += __uint_as_float((v).z << 16); acc[5] += __uint_as_float((v).z & 0xffff0000u); \
    acc[6] += __uint_as_float((v).w << 16); acc[7] += __uint_as_float((v).w & 0xffff0000u); } while (0)
            for (; e + 4 <= end; e += 4) {
                int s0 = sorted_src[e + 0];
                int s1 = sorted_src[e + 1];
                int s2 = sorted_src[e + 2];
                int s3 = sorted_src[e + 3];
                uint4 v0 = z4[(size_t)s0 * 16 + lane];
                uint4 v1 = z4[(size_t)s1 * 16 + lane];
                uint4 v2 = z4[(size_t)s2 * 16 + lane];
                uint4 v3 = z4[(size_t)s3 * 16 + lane];
                ADDV(v0); ADDV(v1); ADDV(v2); ADDV(v3);
            }
            for (; e < end; e++) {
                uint4 v = z4[(size_t)sorted_src[e] * 16 + lane];
                ADDV(v);
            }
#undef ADDV
            float4 b0 = ((const float4*)b)[lane * 2];
            float4 b1 = ((const float4*)b)[lane * 2 + 1];
            float4* o = (float4*)(out + (size_t)node * D + lane * 8);
            o[0] = make_float4(fmaxf(acc[0] + b0.x, 0.f), fmaxf(acc[1] + b0.y, 0.f),
                               fmaxf(acc[2] + b0.z, 0.f), fmaxf(acc[3] + b0.w, 0.f));
            o[1] = make_float4(fmaxf(acc[4] + b1.x, 0.f), fmaxf(acc[5] + b1.y, 0.f),
                               fmaxf(acc[6] + b1.z, 0.f), fmaxf(acc[7] + b1.w, 0.f));
        }
    }
}

// ===================== round-9 split kernels (fallback) =====================

__global__ __launch_bounds__(256) void p1_partition_kernel(
    const int* __restrict__ esrc, const int* __restrict__ edst,
    int* __restrict__ bucketCur, unsigned int* __restrict__ pairs,
    int n_edges, int cap)
{
    __shared__ int hist[256];
    __shared__ int lbase[256];
    __shared__ int gbase[256];
    __shared__ int cur[256];
    __shared__ unsigned int buf[P1_EPB];
    __shared__ unsigned char bkt8[P1_EPB];
    const int tid = threadIdx.x;
    const int base = blockIdx.x * P1_EPB;
    hist[tid] = 0;
    __syncthreads();
    unsigned int pk[16]; int bk[16];
    #pragma unroll
    for (int k = 0; k < 16; k++) {
        int e = base + k * 256 + tid;
        if (e < n_edges) {
            int sv = esrc[e], dv = edst[e];
            bk[k] = dv >> BKT_SHIFT;
            pk[k] = ((unsigned)sv << BKT_SHIFT) | (unsigned)(dv & (BKT_SIZE - 1));
            atomicAdd(&hist[bk[k]], 1);
        } else bk[k] = -1;
    }
    __syncthreads();
    const int v = hist[tid];
    if (v > 0) {
        int res = atomicAdd(&bucketCur[tid], v);
        if (res > cap) res = cap;
        gbase[tid] = tid * cap + res;
    }
    lbase[tid] = v;
    __syncthreads();
    #pragma unroll
    for (int off = 1; off < 256; off <<= 1) {
        int x = (tid >= off) ? lbase[tid - off] : 0;
        __syncthreads();
        lbase[tid] += x;
        __syncthreads();
    }
    const int excl = lbase[tid] - v;
    __syncthreads();
    lbase[tid] = excl;
    cur[tid] = excl;
    __syncthreads();
    #pragma unroll
    for (int k = 0; k < 16; k++) {
        if (bk[k] >= 0) {
            int loc = atomicAdd(&cur[bk[k]], 1);
            buf[loc] = pk[k];
            bkt8[loc] = (unsigned char)bk[k];
        }
    }
    __syncthreads();
    const int total = min(P1_EPB, n_edges - base);
    for (int i = tid; i < total; i += 256) {
        int b = bkt8[i];
        pairs[(size_t)gbase[b] + (i - lbase[b])] = buf[i];
    }
}

__global__ __launch_bounds__(256) void p2_sort_gemm_kernel(
    const unsigned int* __restrict__ pairs, const int* __restrict__ bucketCur,
    int* __restrict__ sorted_src, int* __restrict__ gstart, int* __restrict__ gend,
    const float* __restrict__ h, const float* __restrict__ W,
    unsigned short* __restrict__ z,
    int n_nodes, int nbk, int cap)
{
    __shared__ union SU {
        struct { int hist[BKT_SIZE]; int cur[BKT_SIZE]; int sb[256]; } s;
        unsigned int sW[128 * SW_LDU];
    } u;
    const int tid = threadIdx.x;

    if ((int)blockIdx.x < nbk) {
        const int bkt = blockIdx.x;
        const int nbase = bkt << BKT_SHIFT;
        const int pstart = bkt * cap;
        int cnt = bucketCur[bkt];
        if (cnt > cap) cnt = cap;
        const int pend = pstart + cnt;
        u.s.hist[tid] = 0; u.s.hist[tid + 256] = 0;
        __syncthreads();
        {
            int j = pstart + tid;
            for (; j + 768 < pend; j += 1024) {
                unsigned int q0 = pairs[j];
                unsigned int q1 = pairs[j + 256];
                unsigned int q2 = pairs[j + 512];
                unsigned int q3 = pairs[j + 768];
                atomicAdd(&u.s.hist[q0 & (BKT_SIZE - 1)], 1);
                atomicAdd(&u.s.hist[q1 & (BKT_SIZE - 1)], 1);
                atomicAdd(&u.s.hist[q2 & (BKT_SIZE - 1)], 1);
                atomicAdd(&u.s.hist[q3 & (BKT_SIZE - 1)], 1);
            }
            for (; j < pend; j += 256)
                atomicAdd(&u.s.hist[pairs[j] & (BKT_SIZE - 1)], 1);
        }
        __syncthreads();
        int a  = u.s.hist[2 * tid];
        int b2 = u.s.hist[2 * tid + 1];
        int psum = a + b2;
        u.s.sb[tid] = psum;
        __syncthreads();
        #pragma unroll
        for (int off = 1; off < 256; off <<= 1) {
            int x = (tid >= off) ? u.s.sb[tid - off] : 0;
            __syncthreads();
            u.s.sb[tid] += x;
            __syncthreads();
        }
        int pexcl = u.s.sb[tid] - psum;
        u.s.cur[2 * tid] = pexcl;
        u.s.cur[2 * tid + 1] = pexcl + a;
        __syncthreads();
        for (int i = tid; i < BKT_SIZE; i += 256) {
            int nd = nbase + i;
            if (nd < n_nodes) {
                int st = pstart + u.s.cur[i];
                gstart[nd] = st;
                gend[nd] = st + u.s.hist[i];
            }
        }
        __syncthreads();
        {
            int j = pstart + tid;
            for (; j + 768 < pend; j += 1024) {
                unsigned int q0 = pairs[j];
                unsigned int q1 = pairs[j + 256];
                unsigned int q2 = pairs[j + 512];
                unsigned int q3 = pairs[j + 768];
                int p0 = pstart + atomicAdd(&u.s.cur[q0 & (BKT_SIZE - 1)], 1);
                int p1 = pstart + atomicAdd(&u.s.cur[q1 & (BKT_SIZE - 1)], 1);
                int p2 = pstart + atomicAdd(&u.s.cur[q2 & (BKT_SIZE - 1)], 1);
                int p3 = pstart + atomicAdd(&u.s.cur[q3 & (BKT_SIZE - 1)], 1);
                sorted_src[p0] = (int)(q0 >> BKT_SHIFT);
                sorted_src[p1] = (int)(q1 >> BKT_SHIFT);
                sorted_src[p2] = (int)(q2 >> BKT_SHIFT);
                sorted_src[p3] = (int)(q3 >> BKT_SHIFT);
            }
            for (; j < pend; j += 256) {
                unsigned int p = pairs[j];
                int local = p & (BKT_SIZE - 1);
                int pos = pstart + atomicAdd(&u.s.cur[local], 1);
                sorted_src[pos] = (int)(p >> BKT_SHIFT);
            }
        }
    } else {
        const int gbid = blockIdx.x - nbk;
        for (int i = tid; i < 4096; i += 256) {
            float4 w = ((const float4*)W)[i];
            int row = i >> 5, c4 = i & 31;
            unsigned int* dst = &u.sW[row * SW_LDU + c4 * 2];
            dst[0] = pack2bf(w.x, w.y);
            dst[1] = pack2bf(w.z, w.w);
        }
        __syncthreads();

        const int wave = tid >> 6;
        const int lane = tid & 63;
        const int m = lane & 15;
        const int q = lane >> 4;
        const int r0 = gbid * 64 + wave * 16;
        const int arow = r0 + m;
        const bool rvalid = arow < n_nodes;

        bf16x8 afrag[4];
        #pragma unroll
        for (int ks = 0; ks < 4; ks++) {
            float4 x = make_float4(0.f, 0.f, 0.f, 0.f), y = x;
            if (rvalid) {
                const float4* p = (const float4*)(h + (size_t)arow * D + ks * 32 + q * 8);
                x = p[0]; y = p[1];
            }
            union { unsigned int uu[4]; bf16x8 v; } cvt;
            cvt.uu[0] = pack2bf(x.x, x.y);
            cvt.uu[1] = pack2bf(x.z, x.w);
            cvt.uu[2] = pack2bf(y.x, y.y);
            cvt.uu[3] = pack2bf(y.z, y.w);
            afrag[ks] = cvt.v;
        }

        f32x4 acc[8];
        #pragma unroll
        for (int ct = 0; ct < 8; ct++) acc[ct] = (f32x4){0.f, 0.f, 0.f, 0.f};

        #pragma unroll
        for (int ct = 0; ct < 8; ct++) {
            #pragma unroll
            for (int ks = 0; ks < 4; ks++) {
                const unsigned int* p = &u.sW[(ct * 16 + m) * SW_LDU + ks * 16 + q * 4];
                union { uint4 uu; bf16x8 v; } bu;
                bu.uu = *(const uint4*)p;
                acc[ct] = __builtin_amdgcn_mfma_f32_16x16x32_bf16(afrag[ks], bu.v, acc[ct], 0, 0, 0);
            }
        }

        __syncthreads();
        unsigned short* lds_us = (unsigned short*)u.sW;
        #pragma unroll
        for (int ct = 0; ct < 8; ct++) {
            #pragma unroll
            for (int i = 0; i < 4; i++) {
                lds_us[(wave * 16 + q * 4 + i) * 130 + ct * 16 + m] = pack1bf(acc[ct][i]);
            }
        }
        __syncthreads();
        const unsigned int* lds32 = (const unsigned int*)u.sW;
        const int r0blk = gbid * 64;
        #pragma unroll
        for (int pass = 0; pass < 4; pass++) {
            int idx = pass * 256 + tid;
            int row = idx >> 4;
            int c16 = idx & 15;
            int r = r0blk + row;
            if (r < n_nodes) {
                int bo = row * 65 + c16 * 4;
                uint4 val;
                val.x = lds32[bo]; val.y = lds32[bo + 1];
                val.z = lds32[bo + 2]; val.w = lds32[bo + 3];
                ((uint4*)z)[(size_t)r * 16 + c16] = val;
            }
        }
    }
}

__global__ __launch_bounds__(256) void gather_row_kernel(
    const unsigned short* __restrict__ z, const int* __restrict__ gstart,
    const int* __restrict__ gend, const int* __restrict__ sorted_src,
    const float* __restrict__ b, float* __restrict__ out, int n_nodes)
{
    const int tid = threadIdx.x;
    const int node = blockIdx.x * 16 + (tid >> 4);
    const int lane = tid & 15;
    if (node >= n_nodes) return;
    int e = gstart[node];
    const int end = gend[node];
    const uint4* __restrict__ z4 = (const uint4*)z;
    float acc[8];
    #pragma unroll
    for (int i = 0; i < 8; i++) acc[i] = 0.f;
#define ADDV(v) do { \
    acc[0] += __uint_as_float((v).x << 16); acc[1] += __uint_as_float((v).x & 0xffff0000u); \
    acc[2] += __uint_as_float((v).y << 16); acc[3] += __uint_as_float((v).y & 0xffff0000u); \
    acc[4] += __uint_as_float((v).z << 16); acc[5] += __uint_as_float((v).z & 0xffff0000u); \
    acc[6] += __uint_as_float((v).w << 16); acc[7] += __uint_as_float((v).w & 0xffff0000u); } while (0)
    for (; e + 4 <= end; e += 4) {
        int s0 = sorted_src[e + 0];
        int s1 = sorted_src[e + 1];
        int s2 = sorted_src[e + 2];
        int s3 = sorted_src[e + 3];
        uint4 v0 = z4[(size_t)s0 * 16 + lane];
        uint4 v1 = z4[(size_t)s1 * 16 + lane];
        uint4 v2 = z4[(size_t)s2 * 16 + lane];
        uint4 v3 = z4[(size_t)s3 * 16 + lane];
        ADDV(v0); ADDV(v1); ADDV(v2); ADDV(v3);
    }
    for (; e < end; e++) {
        uint4 v = z4[(size_t)sorted_src[e] * 16 + lane];
        ADDV(v);
    }
#undef ADDV
    float4 b0 = ((const float4*)b)[lane * 2];
    float4 b1 = ((const float4*)b)[lane * 2 + 1];
    float4* o = (float4*)(out + (size_t)node * D + lane * 8);
    o[0] = make_float4(fmaxf(acc[0] + b0.x, 0.f), fmaxf(acc[1] + b0.y, 0.f),
                       fmaxf(acc[2] + b0.z, 0.f), fmaxf(acc[3] + b0.w, 0.f));
    o[1] = make_float4(fmaxf(acc[4] + b1.x, 0.f), fmaxf(acc[5] + b1.y, 0.f),
                       fmaxf(acc[6] + b1.z, 0.f), fmaxf(acc[7] + b1.w, 0.f));
}

// ===================== last-resort fallback =====================

__global__ __launch_bounds__(256) void scatter_kernel(
    const float* __restrict__ h, const int* __restrict__ esrc,
    const int* __restrict__ edst, float* __restrict__ out, int n_edges)
{
    int gid = blockIdx.x * 256 + threadIdx.x;
    int e = gid >> 5;
    int l = gid & 31;
    if (e >= n_edges) return;
    int s = esrc[e];
    int d = edst[e];
    float4 v = ((const float4*)(h + (size_t)s * D))[l];
    float* o = out + (size_t)d * D + (size_t)l * 4;
    atomicAdd(o + 0, v.x);
    atomicAdd(o + 1, v.y);
    atomicAdd(o + 2, v.z);
    atomicAdd(o + 3, v.w);
}

__global__ __launch_bounds__(256) void mfma_gemm_relu_kernel(
    float* __restrict__ io, const float* __restrict__ W,
    const float* __restrict__ b, int n_nodes)
{
    __shared__ unsigned int sW[128 * SW_LDU];
    const int tid = threadIdx.x;
    for (int i = tid; i < 4096; i += 256) {
        float4 w = ((const float4*)W)[i];
        int row = i >> 5, c4 = i & 31;
        unsigned int* dst = &sW[row * SW_LDU + c4 * 2];
        dst[0] = pack2bf(w.x, w.y);
        dst[1] = pack2bf(w.z, w.w);
    }
    __syncthreads();
    const int wave = tid >> 6;
    const int lane = tid & 63;
    const int m = lane & 15;
    const int q = lane >> 4;
    const int r0 = blockIdx.x * 64 + wave * 16;
    const int arow = r0 + m;
    const bool rvalid = arow < n_nodes;
    bf16x8 afrag[4];
    #pragma unroll
    for (int ks = 0; ks < 4; ks++) {
        float4 x = make_float4(0.f, 0.f, 0.f, 0.f), y = x;
        if (rvalid) {
            const float4* p = (const float4*)(io + (size_t)arow * D + ks * 32 + q * 8);
            x = p[0]; y = p[1];
        }
        union { unsigned int u[4]; bf16x8 v; } cvt;
        cvt.u[0] = pack2bf(x.x, x.y);
        cvt.u[1] = pack2bf(x.z, x.w);
        cvt.u[2] = pack2bf(y.x, y.y);
        cvt.u[3] = pack2bf(y.z, y.w);
        afrag[ks] = cvt.v;
    }
    f32x4 acc[8];
    #pragma unroll
    for (int ct = 0; ct < 8; ct++) acc[ct] = (f32x4){0.f, 0.f, 0.f, 0.f};
    #pragma unroll
    for (int ct = 0; ct < 8; ct++) {
        #pragma unroll
        for (int ks = 0; ks < 4; ks++) {
            const unsigned int* p = &sW[(ct * 16 + m) * SW_LDU + ks * 16 + q * 4];
            union { uint4 u; bf16x8 v; } bu;
            bu.u = *(const uint4*)p;
            acc[ct] = __builtin_amdgcn_mfma_f32_16x16x32_bf16(afrag[ks], bu.v, acc[ct], 0, 0, 0);
        }
    }
    #pragma unroll
    for (int ct = 0; ct < 8; ct++) {
        int col = ct * 16 + m;
        float bias = b[col];
        #pragma unroll
        for (int i = 0; i < 4; i++) {
            int r = r0 + q * 4 + i;
            if (r < n_nodes) {
                float v = acc[ct][i] + bias;
                io[(size_t)r * D + col] = v > 0.f ? v : 0.f;
            }
        }
    }
}

extern "C" void kernel_launch(void* const* d_in, const int* in_sizes, int n_in,
                              void* d_out, int out_size, void* d_ws, size_t ws_size,
                              hipStream_t stream) {
    const float* h    = (const float*)d_in[0];
    const int*   esrc = (const int*)d_in[1];
    const int*   edst = (const int*)d_in[2];
    const float* W    = (const float*)d_in[3];
    const float* b    = (const float*)d_in[4];
    float* out = (float*)d_out;
    const int n_nodes = in_sizes[0] / D;
    const int n_edges = in_sizes[1];
    const int NBK = (n_nodes + BKT_SIZE - 1) / BKT_SIZE;
    const int nchunks = (n_edges + P1_EPB - 1) / P1_EPB;

    const int avg = (n_edges + NBK - 1) / NBK;
    const int CAP = (2 * avg + 2047) & ~2047;
    const size_t win = (size_t)NBK * CAP;

    // layout: gstart | gend | bucketCur | counters(16) | sorted_src(win) | pairs(win) | z
    size_t fixed = ((size_t)2 * n_nodes + NBK + 16 + 2 * win) * 4;
    size_t z_off = (fixed + 15) & ~(size_t)15;
    size_t need = z_off + (size_t)n_nodes * D * 2;

    if (ws_size >= need && NBK <= 256 && n_nodes <= (1 << 22)) {
        int* gstart     = (int*)d_ws;               // n_nodes
        int* gend       = gstart + n_nodes;         // n_nodes
        int* bucketCur  = gend + n_nodes;           // NBK
        int* counters   = bucketCur + NBK;          // 16
        int* sorted_src = counters + 16;            // win
        unsigned int* pairs = (unsigned int*)(sorted_src + win);
        unsigned short* z   = (unsigned short*)((char*)d_ws + z_off);

        const int gemmBlocks = (n_nodes + 63) / 64;
        const int nGather = (n_nodes + 15) / 16;

        // occupancy-derived cooperative grid (cached across calls)
        static int s_coop_grid = -2;
        if (s_coop_grid == -2) {
            int nb = 0;
            hipError_t err = hipOccupancyMaxActiveBlocksPerMultiprocessor(
                &nb, (const void*)mega_kernel, 256, 0);
            if (err != hipSuccess || nb < 1) {
                s_coop_grid = -1;
            } else {
                hipDeviceProp_t prop{};
                int dev = 0;
                if (hipGetDevice(&dev) == hipSuccess &&
                    hipGetDeviceProperties(&prop, dev) == hipSuccess &&
                    prop.multiProcessorCount > 0 &&
                    prop.cooperativeLaunch)
                    s_coop_grid = nb * prop.multiProcessorCount;
                else
                    s_coop_grid = -1;
            }
        }

        if (s_coop_grid >= 64) {
            int grid = s_coop_grid > 4096 ? 4096 : s_coop_grid;
            int ne = n_edges, nn = n_nodes, nb = NBK, cp = CAP, nc = nchunks;
            int gb = gemmBlocks, ng = nGather;
            void* args[] = {
                (void*)&esrc, (void*)&edst, (void*)&h, (void*)&W, (void*)&b,
                (void*)&out, (void*)&bucketCur, (void*)&gstart, (void*)&gend,
                (void*)&sorted_src, (void*)&pairs, (void*)&z, (void*)&counters,
                (void*)&nn, (void*)&ne, (void*)&nb, (void*)&cp, (void*)&nc,
                (void*)&gb, (void*)&ng };
            if (hipLaunchCooperativeKernel((void*)mega_kernel, dim3(grid),
                                           dim3(256), args, 0, stream) == hipSuccess)
                return;
            s_coop_grid = -1;   // coop failed: fall through to split path forever
        }

        // ---- proven 4-dispatch split path ----
        hipMemsetAsync(bucketCur, 0, (size_t)NBK * sizeof(int), stream);
        p1_partition_kernel<<<nchunks, 256, 0, stream>>>(
            esrc, edst, bucketCur, pairs, n_edges, CAP);
        p2_sort_gemm_kernel<<<NBK + gemmBlocks, 256, 0, stream>>>(
            pairs, bucketCur, sorted_src, gstart, gend, h, W, z,
            n_nodes, NBK, CAP);
        gather_row_kernel<<<nGather, 256, 0, stream>>>(
            z, gstart, gend, sorted_src, b, out, n_nodes);
        return;
    }

    // ---- last-resort fallback: fp32 scatter + in-place mfma gemm ----
    hipMemsetAsync(out, 0, (size_t)n_nodes * D * sizeof(float), stream);
    long long total = (long long)n_edges * 32;
    scatter_kernel<<<(int)((total + 255) / 256), 256, 0, stream>>>(h, esrc, edst, out, n_edges);
    mfma_gemm_relu_kernel<<<(n_nodes + 63) / 64, 256, 0, stream>>>(out, W, b, n_nodes);
}

// Round 11
// 222.687 us; speedup vs baseline: 2.2250x; 2.2250x over previous
//
#include <hip/hip_runtime.h>

#define D 128
#define BKT_SHIFT 9
#define BKT_SIZE 512
#define P1_EPB 4096
#define SW_LDU 68   // uints per W row in LDS (136 ushorts = 128 + 8 pad)

typedef __attribute__((ext_vector_type(8))) short bf16x8;
typedef __attribute__((ext_vector_type(4))) float f32x4;

__device__ inline unsigned int pack2bf(float a, float b) {
    unsigned int ua = __float_as_uint(a);
    unsigned int ub = __float_as_uint(b);
    ua = (ua + 0x7fffu + ((ua >> 16) & 1u)) >> 16;   // RNE
    ub = (ub + 0x7fffu + ((ub >> 16) & 1u)) >> 16;
    return ua | (ub << 16);
}
__device__ inline unsigned short pack1bf(float a) {
    unsigned int ua = __float_as_uint(a);
    return (unsigned short)((ua + 0x7fffu + ((ua >> 16) & 1u)) >> 16);
}

// ============ fixed-capacity bucket CSR (round-9 proven bodies) ============
// D1: memset bucketCur (NBK ints)
// D2: p1 partition (blocks [0,nchunks)) FUSED with GEMM z=bf16(h@W^T)
//     (blocks [nchunks,...)) — both depend only on inputs + memset, so the
//     GEMM hides under p1 instead of sitting on the critical path.
// D3: bucket sort alone (196 blocks, L2-resident, cheap)
// D4: full-row gather + bias + relu

// D2: fused p1 + GEMM
__global__ __launch_bounds__(256) void p1_gemm_kernel(
    const int* __restrict__ esrc, const int* __restrict__ edst,
    int* __restrict__ bucketCur, unsigned int* __restrict__ pairs,
    const float* __restrict__ h, const float* __restrict__ W,
    unsigned short* __restrict__ z,
    int n_edges, int n_nodes, int nchunks, int cap)
{
    __shared__ union U {
        struct { int hist[256]; int lbase[256]; int gbase[256]; int cur[256];
                 unsigned int buf[P1_EPB]; unsigned char bkt8[P1_EPB]; } p1;
        unsigned int sW[128 * SW_LDU];
    } u;
    const int tid = threadIdx.x;

    if ((int)blockIdx.x < nchunks) {
        // ---------- p1 partition ----------
        const int base = blockIdx.x * P1_EPB;
        u.p1.hist[tid] = 0;
        __syncthreads();
        unsigned int pk[16]; int bk[16];
        #pragma unroll
        for (int k = 0; k < 16; k++) {
            int e = base + k * 256 + tid;
            if (e < n_edges) {
                int sv = esrc[e], dv = edst[e];
                bk[k] = dv >> BKT_SHIFT;
                pk[k] = ((unsigned)sv << BKT_SHIFT) | (unsigned)(dv & (BKT_SIZE - 1));
                atomicAdd(&u.p1.hist[bk[k]], 1);
            } else bk[k] = -1;
        }
        __syncthreads();
        const int v = u.p1.hist[tid];
        if (v > 0) {
            int res = atomicAdd(&bucketCur[tid], v);
            if (res > cap) res = cap;
            u.p1.gbase[tid] = tid * cap + res;
        }
        u.p1.lbase[tid] = v;
        __syncthreads();
        #pragma unroll
        for (int off = 1; off < 256; off <<= 1) {
            int x = (tid >= off) ? u.p1.lbase[tid - off] : 0;
            __syncthreads();
            u.p1.lbase[tid] += x;
            __syncthreads();
        }
        const int excl = u.p1.lbase[tid] - v;
        __syncthreads();
        u.p1.lbase[tid] = excl;
        u.p1.cur[tid] = excl;
        __syncthreads();
        #pragma unroll
        for (int k = 0; k < 16; k++) {
            if (bk[k] >= 0) {
                int loc = atomicAdd(&u.p1.cur[bk[k]], 1);
                u.p1.buf[loc] = pk[k];
                u.p1.bkt8[loc] = (unsigned char)bk[k];
            }
        }
        __syncthreads();
        const int total = min(P1_EPB, n_edges - base);
        for (int i = tid; i < total; i += 256) {
            int b = u.p1.bkt8[i];
            pairs[(size_t)u.p1.gbase[b] + (i - u.p1.lbase[b])] = u.p1.buf[i];
        }
    } else {
        // ---------- GEMM: z = bf16(h @ W^T) ----------
        const int gbid = blockIdx.x - nchunks;
        for (int i = tid; i < 4096; i += 256) {
            float4 w = ((const float4*)W)[i];
            int row = i >> 5, c4 = i & 31;
            unsigned int* dst = &u.sW[row * SW_LDU + c4 * 2];
            dst[0] = pack2bf(w.x, w.y);
            dst[1] = pack2bf(w.z, w.w);
        }
        __syncthreads();

        const int wave = tid >> 6;
        const int lane = tid & 63;
        const int m = lane & 15;
        const int q = lane >> 4;
        const int r0 = gbid * 64 + wave * 16;
        const int arow = r0 + m;
        const bool rvalid = arow < n_nodes;

        bf16x8 afrag[4];
        #pragma unroll
        for (int ks = 0; ks < 4; ks++) {
            float4 x = make_float4(0.f, 0.f, 0.f, 0.f), y = x;
            if (rvalid) {
                const float4* p = (const float4*)(h + (size_t)arow * D + ks * 32 + q * 8);
                x = p[0]; y = p[1];
            }
            union { unsigned int uu[4]; bf16x8 v; } cvt;
            cvt.uu[0] = pack2bf(x.x, x.y);
            cvt.uu[1] = pack2bf(x.z, x.w);
            cvt.uu[2] = pack2bf(y.x, y.y);
            cvt.uu[3] = pack2bf(y.z, y.w);
            afrag[ks] = cvt.v;
        }

        f32x4 acc[8];
        #pragma unroll
        for (int ct = 0; ct < 8; ct++) acc[ct] = (f32x4){0.f, 0.f, 0.f, 0.f};

        #pragma unroll
        for (int ct = 0; ct < 8; ct++) {
            #pragma unroll
            for (int ks = 0; ks < 4; ks++) {
                const unsigned int* p = &u.sW[(ct * 16 + m) * SW_LDU + ks * 16 + q * 4];
                union { uint4 uu; bf16x8 v; } bu;
                bu.uu = *(const uint4*)p;
                acc[ct] = __builtin_amdgcn_mfma_f32_16x16x32_bf16(afrag[ks], bu.v, acc[ct], 0, 0, 0);
            }
        }

        // LDS-staged epilogue: bf16 tile [64][130-pad], then coalesced uint4 stores
        __syncthreads();
        unsigned short* lds_us = (unsigned short*)u.sW;
        #pragma unroll
        for (int ct = 0; ct < 8; ct++) {
            #pragma unroll
            for (int i = 0; i < 4; i++) {
                lds_us[(wave * 16 + q * 4 + i) * 130 + ct * 16 + m] = pack1bf(acc[ct][i]);
            }
        }
        __syncthreads();
        const unsigned int* lds32 = (const unsigned int*)u.sW;
        const int r0blk = gbid * 64;
        #pragma unroll
        for (int pass = 0; pass < 4; pass++) {
            int idx = pass * 256 + tid;      // 0..1023
            int row = idx >> 4;
            int c16 = idx & 15;
            int r = r0blk + row;
            if (r < n_nodes) {
                int bo = row * 65 + c16 * 4;
                uint4 val;
                val.x = lds32[bo]; val.y = lds32[bo + 1];
                val.z = lds32[bo + 2]; val.w = lds32[bo + 3];
                ((uint4*)z)[(size_t)r * 16 + c16] = val;
            }
        }
    }
}

// D3: bucket sort (one block per bucket)
__global__ __launch_bounds__(256) void p2_sort_kernel(
    const unsigned int* __restrict__ pairs, const int* __restrict__ bucketCur,
    int* __restrict__ sorted_src, int* __restrict__ gstart, int* __restrict__ gend,
    int n_nodes, int nbk, int cap)
{
    __shared__ int hist[BKT_SIZE];
    __shared__ int cur[BKT_SIZE];
    __shared__ int sb[256];
    const int tid = threadIdx.x;
    const int bkt = blockIdx.x;
    const int nbase = bkt << BKT_SHIFT;
    const int pstart = bkt * cap;
    int cnt = bucketCur[bkt];
    if (cnt > cap) cnt = cap;
    const int pend = pstart + cnt;
    hist[tid] = 0; hist[tid + 256] = 0;
    __syncthreads();
    {
        int j = pstart + tid;
        for (; j + 768 < pend; j += 1024) {
            unsigned int q0 = pairs[j];
            unsigned int q1 = pairs[j + 256];
            unsigned int q2 = pairs[j + 512];
            unsigned int q3 = pairs[j + 768];
            atomicAdd(&hist[q0 & (BKT_SIZE - 1)], 1);
            atomicAdd(&hist[q1 & (BKT_SIZE - 1)], 1);
            atomicAdd(&hist[q2 & (BKT_SIZE - 1)], 1);
            atomicAdd(&hist[q3 & (BKT_SIZE - 1)], 1);
        }
        for (; j < pend; j += 256)
            atomicAdd(&hist[pairs[j] & (BKT_SIZE - 1)], 1);
    }
    __syncthreads();
    int a  = hist[2 * tid];
    int b2 = hist[2 * tid + 1];
    int psum = a + b2;
    sb[tid] = psum;
    __syncthreads();
    #pragma unroll
    for (int off = 1; off < 256; off <<= 1) {
        int x = (tid >= off) ? sb[tid - off] : 0;
        __syncthreads();
        sb[tid] += x;
        __syncthreads();
    }
    int pexcl = sb[tid] - psum;
    cur[2 * tid] = pexcl;
    cur[2 * tid + 1] = pexcl + a;
    __syncthreads();
    for (int i = tid; i < BKT_SIZE; i += 256) {
        int nd = nbase + i;
        if (nd < n_nodes) {
            int st = pstart + cur[i];
            gstart[nd] = st;
            gend[nd] = st + hist[i];
        }
    }
    __syncthreads();
    {
        int j = pstart + tid;
        for (; j + 768 < pend; j += 1024) {
            unsigned int q0 = pairs[j];
            unsigned int q1 = pairs[j + 256];
            unsigned int q2 = pairs[j + 512];
            unsigned int q3 = pairs[j + 768];
            int p0 = pstart + atomicAdd(&cur[q0 & (BKT_SIZE - 1)], 1);
            int p1 = pstart + atomicAdd(&cur[q1 & (BKT_SIZE - 1)], 1);
            int p2 = pstart + atomicAdd(&cur[q2 & (BKT_SIZE - 1)], 1);
            int p3 = pstart + atomicAdd(&cur[q3 & (BKT_SIZE - 1)], 1);
            sorted_src[p0] = (int)(q0 >> BKT_SHIFT);
            sorted_src[p1] = (int)(q1 >> BKT_SHIFT);
            sorted_src[p2] = (int)(q2 >> BKT_SHIFT);
            sorted_src[p3] = (int)(q3 >> BKT_SHIFT);
        }
        for (; j < pend; j += 256) {
            unsigned int p = pairs[j];
            int local = p & (BKT_SIZE - 1);
            int pos = pstart + atomicAdd(&cur[local], 1);
            sorted_src[pos] = (int)(p >> BKT_SHIFT);
        }
    }
}

// D4: full-row gather + bias + relu
__global__ __launch_bounds__(256) void gather_row_kernel(
    const unsigned short* __restrict__ z, const int* __restrict__ gstart,
    const int* __restrict__ gend, const int* __restrict__ sorted_src,
    const float* __restrict__ b, float* __restrict__ out, int n_nodes)
{
    const int tid = threadIdx.x;
    const int node = blockIdx.x * 16 + (tid >> 4);
    const int lane = tid & 15;
    if (node >= n_nodes) return;
    int e = gstart[node];
    const int end = gend[node];
    const uint4* __restrict__ z4 = (const uint4*)z;   // 16 uint4 per row
    float acc[8];
    #pragma unroll
    for (int i = 0; i < 8; i++) acc[i] = 0.f;
#define ADDV(v) do { \
    acc[0] += __uint_as_float((v).x << 16); acc[1] += __uint_as_float((v).x & 0xffff0000u); \
    acc[2] += __uint_as_float((v).y << 16); acc[3] += __uint_as_float((v).y & 0xffff0000u); \
    acc[4] += __uint_as_float((v).z << 16); acc[5] += __uint_as_float((v).z & 0xffff0000u); \
    acc[6] += __uint_as_float((v).w << 16); acc[7] += __uint_as_float((v).w & 0xffff0000u); } while (0)
    for (; e + 4 <= end; e += 4) {
        int s0 = sorted_src[e + 0];
        int s1 = sorted_src[e + 1];
        int s2 = sorted_src[e + 2];
        int s3 = sorted_src[e + 3];
        uint4 v0 = z4[(size_t)s0 * 16 + lane];
        uint4 v1 = z4[(size_t)s1 * 16 + lane];
        uint4 v2 = z4[(size_t)s2 * 16 + lane];
        uint4 v3 = z4[(size_t)s3 * 16 + lane];
        ADDV(v0); ADDV(v1); ADDV(v2); ADDV(v3);
    }
    for (; e < end; e++) {
        uint4 v = z4[(size_t)sorted_src[e] * 16 + lane];
        ADDV(v);
    }
#undef ADDV
    float4 b0 = ((const float4*)b)[lane * 2];
    float4 b1 = ((const float4*)b)[lane * 2 + 1];
    float4* o = (float4*)(out + (size_t)node * D + lane * 8);
    o[0] = make_float4(fmaxf(acc[0] + b0.x, 0.f), fmaxf(acc[1] + b0.y, 0.f),
                       fmaxf(acc[2] + b0.z, 0.f), fmaxf(acc[3] + b0.w, 0.f));
    o[1] = make_float4(fmaxf(acc[4] + b1.x, 0.f), fmaxf(acc[5] + b1.y, 0.f),
                       fmaxf(acc[6] + b1.z, 0.f), fmaxf(acc[7] + b1.w, 0.f));
}

// ================= last-resort fallback =================

__global__ __launch_bounds__(256) void scatter_kernel(
    const float* __restrict__ h, const int* __restrict__ esrc,
    const int* __restrict__ edst, float* __restrict__ out, int n_edges)
{
    int gid = blockIdx.x * 256 + threadIdx.x;
    int e = gid >> 5;
    int l = gid & 31;
    if (e >= n_edges) return;
    int s = esrc[e];
    int d = edst[e];
    float4 v = ((const float4*)(h + (size_t)s * D))[l];
    float* o = out + (size_t)d * D + (size_t)l * 4;
    atomicAdd(o + 0, v.x);
    atomicAdd(o + 1, v.y);
    atomicAdd(o + 2, v.z);
    atomicAdd(o + 3, v.w);
}

__global__ __launch_bounds__(256) void mfma_gemm_relu_kernel(
    float* __restrict__ io, const float* __restrict__ W,
    const float* __restrict__ b, int n_nodes)
{
    __shared__ unsigned int sW[128 * SW_LDU];
    const int tid = threadIdx.x;
    for (int i = tid; i < 4096; i += 256) {
        float4 w = ((const float4*)W)[i];
        int row = i >> 5, c4 = i & 31;
        unsigned int* dst = &sW[row * SW_LDU + c4 * 2];
        dst[0] = pack2bf(w.x, w.y);
        dst[1] = pack2bf(w.z, w.w);
    }
    __syncthreads();
    const int wave = tid >> 6;
    const int lane = tid & 63;
    const int m = lane & 15;
    const int q = lane >> 4;
    const int r0 = blockIdx.x * 64 + wave * 16;
    const int arow = r0 + m;
    const bool rvalid = arow < n_nodes;
    bf16x8 afrag[4];
    #pragma unroll
    for (int ks = 0; ks < 4; ks++) {
        float4 x = make_float4(0.f, 0.f, 0.f, 0.f), y = x;
        if (rvalid) {
            const float4* p = (const float4*)(io + (size_t)arow * D + ks * 32 + q * 8);
            x = p[0]; y = p[1];
        }
        union { unsigned int u[4]; bf16x8 v; } cvt;
        cvt.u[0] = pack2bf(x.x, x.y);
        cvt.u[1] = pack2bf(x.z, x.w);
        cvt.u[2] = pack2bf(y.x, y.y);
        cvt.u[3] = pack2bf(y.z, y.w);
        afrag[ks] = cvt.v;
    }
    f32x4 acc[8];
    #pragma unroll
    for (int ct = 0; ct < 8; ct++) acc[ct] = (f32x4){0.f, 0.f, 0.f, 0.f};
    #pragma unroll
    for (int ct = 0; ct < 8; ct++) {
        #pragma unroll
        for (int ks = 0; ks < 4; ks++) {
            const unsigned int* p = &sW[(ct * 16 + m) * SW_LDU + ks * 16 + q * 4];
            union { uint4 u; bf16x8 v; } bu;
            bu.u = *(const uint4*)p;
            acc[ct] = __builtin_amdgcn_mfma_f32_16x16x32_bf16(afrag[ks], bu.v, acc[ct], 0, 0, 0);
        }
    }
    #pragma unroll
    for (int ct = 0; ct < 8; ct++) {
        int col = ct * 16 + m;
        float bias = b[col];
        #pragma unroll
        for (int i = 0; i < 4; i++) {
            int r = r0 + q * 4 + i;
            if (r < n_nodes) {
                float v = acc[ct][i] + bias;
                io[(size_t)r * D + col] = v > 0.f ? v : 0.f;
            }
        }
    }
}

extern "C" void kernel_launch(void* const* d_in, const int* in_sizes, int n_in,
                              void* d_out, int out_size, void* d_ws, size_t ws_size,
                              hipStream_t stream) {
    const float* h    = (const float*)d_in[0];
    const int*   esrc = (const int*)d_in[1];
    const int*   edst = (const int*)d_in[2];
    const float* W    = (const float*)d_in[3];
    const float* b    = (const float*)d_in[4];
    float* out = (float*)d_out;
    const int n_nodes = in_sizes[0] / D;
    const int n_edges = in_sizes[1];
    const int NBK = (n_nodes + BKT_SIZE - 1) / BKT_SIZE;
    const int nchunks = (n_edges + P1_EPB - 1) / P1_EPB;

    // fixed bucket capacity: 2x mean, rounded up to 2048 (overflow ~impossible
    // for near-uniform dst; clamped in-kernel so it can never corrupt memory)
    const int avg = (n_edges + NBK - 1) / NBK;
    const int CAP = (2 * avg + 2047) & ~2047;
    const size_t win = (size_t)NBK * CAP;

    // layout: gstart | gend | bucketCur | sorted_src(win) | pairs(win) | z
    size_t fixed = ((size_t)2 * n_nodes + NBK + 2 * win) * 4;
    size_t z_off = (fixed + 15) & ~(size_t)15;
    size_t need = z_off + (size_t)n_nodes * D * 2;

    if (ws_size >= need && NBK <= 256 && n_nodes <= (1 << 22)) {
        int* gstart     = (int*)d_ws;               // n_nodes
        int* gend       = gstart + n_nodes;         // n_nodes
        int* bucketCur  = gend + n_nodes;           // NBK
        int* sorted_src = bucketCur + NBK;          // win
        unsigned int* pairs = (unsigned int*)(sorted_src + win);
        unsigned short* z   = (unsigned short*)((char*)d_ws + z_off);

        const int gemmBlocks = (n_nodes + 63) / 64;

        hipMemsetAsync(bucketCur, 0, (size_t)NBK * sizeof(int), stream);
        // D2: p1 partition co-dispatched with GEMM (independent work)
        p1_gemm_kernel<<<nchunks + gemmBlocks, 256, 0, stream>>>(
            esrc, edst, bucketCur, pairs, h, W, z,
            n_edges, n_nodes, nchunks, CAP);
        // D3: bucket sort (cheap, L2-resident)
        p2_sort_kernel<<<NBK, 256, 0, stream>>>(
            pairs, bucketCur, sorted_src, gstart, gend, n_nodes, NBK, CAP);
        // D4: gather
        gather_row_kernel<<<(n_nodes + 15) / 16, 256, 0, stream>>>(
            z, gstart, gend, sorted_src, b, out, n_nodes);
        return;
    }

    // ---- last-resort fallback: fp32 scatter + in-place mfma gemm ----
    hipMemsetAsync(out, 0, (size_t)n_nodes * D * sizeof(float), stream);
    long long total = (long long)n_edges * 32;
    scatter_kernel<<<(int)((total + 255) / 256), 256, 0, stream>>>(h, esrc, edst, out, n_edges);
    mfma_gemm_relu_kernel<<<(n_nodes + 63) / 64, 256, 0, stream>>>(out, W, b, n_nodes);
}